// Round 11
// baseline (914.062 us; speedup 1.0000x reference)
//
#include <hip/hip_runtime.h>

#define T_   2
#define IN_  6
#define DIM_ 36
#define LIN_ 54
#define OUT_ 18
#define BN_EPS 1e-5f

#define WSH_   7        // bucket width = 128 dst nodes
#define WMSK_  127
#define CAP_   2560     // per-bucket capacity (mean 2046, 11 sigma headroom)
#define TILE_  6144     // edges per binsort block
#define NBMAX_ 1024     // max buckets supported by in-LDS scan

__device__ __forceinline__ unsigned short f2bf(float f) {
    unsigned u = __float_as_uint(f);
    unsigned r = (u + 0x7FFFu + ((u >> 16) & 1u)) >> 16;    // RNE
    return (unsigned short)r;
}
__device__ __forceinline__ float bf2f(unsigned short h) {
    return __uint_as_float(((unsigned)h) << 16);
}
__device__ __forceinline__ unsigned packbf(float a, float b) {
    return (unsigned)f2bf(a) | ((unsigned)f2bf(b) << 16);
}

// ===========================================================================
// binsort_k: bin edges by dst bucket with LDS staging; coalesced packed
// writes (src 17b | dstoff 7b). Grid covers tc transforms: lt = bid/gbin.
// ===========================================================================
__global__ __launch_bounds__(256) void binsort_k(
    const int* __restrict__ ei, int t0, int gbin,
    int* __restrict__ bcnt, int* __restrict__ bbuf, int ne, int nb)
{
    __shared__ int cntl[NBMAX_], cursl[NBMAX_], gbasel[NBMAX_];
    __shared__ int aux[256];
    __shared__ int sortedl[TILE_];

    const int tid  = threadIdx.x;
    const int lt   = blockIdx.x / gbin;
    const int tile = blockIdx.x % gbin;
    const int base = tile * TILE_;
    const int cnt_e = min(TILE_, ne - base);
    const int* srcp = ei + (size_t)(t0 + lt) * 2 * ne;
    const int* dstp = srcp + ne;
    int* bcnt_t = bcnt + (size_t)lt * nb;

    for (int i = tid; i < NBMAX_; i += 256) cntl[i] = 0;
    __syncthreads();

    for (int i = tid; i < cnt_e; i += 256)
        atomicAdd(&cntl[dstp[base + i] >> WSH_], 1);
    __syncthreads();

    int t4 = tid * 4;
    int c0 = cntl[t4+0], c1 = cntl[t4+1], c2 = cntl[t4+2], c3 = cntl[t4+3];
    int lsum = c0 + c1 + c2 + c3;
    aux[tid] = lsum;
    __syncthreads();
    for (int off = 1; off < 256; off <<= 1) {
        int v = (tid >= off) ? aux[tid - off] : 0;
        __syncthreads();
        aux[tid] += v;
        __syncthreads();
    }
    int eb = aux[tid] - lsum;
    cursl[t4+0] = eb;
    cursl[t4+1] = eb + c0;
    cursl[t4+2] = eb + c0 + c1;
    cursl[t4+3] = eb + c0 + c1 + c2;
    __syncthreads();

    for (int b = tid; b < nb; b += 256) {
        int c = cntl[b];
        gbasel[b] = c ? atomicAdd(&bcnt_t[b], c) : 0;
    }
    __syncthreads();

    for (int i = tid; i < cnt_e; i += 256) {
        int s = srcp[base + i], d = dstp[base + i];
        int p = atomicAdd(&cursl[d >> WSH_], 1);
        sortedl[p] = s | ((d & WMSK_) << 17);
    }
    __syncthreads();

    int wv = tid >> 6, ln = tid & 63;
    for (int b = wv; b < nb; b += 4) {
        int c = cntl[b];
        if (!c) continue;
        int lb = cursl[b] - c;
        int gb = gbasel[b];
        size_t ga = ((size_t)lt * nb + b) * CAP_ + gb;
        for (int i = ln; i < c; i += 64)
            if (gb + i < CAP_) bbuf[ga + i] = sortedl[lb + i];
    }
}

// ===========================================================================
// csrify_k: one block per (t,bucket): sort bucket by dst node in LDS, write
// back coalesced (unpacked src), emit rp (global into bbuf) and deg.
// ===========================================================================
__global__ __launch_bounds__(256) void csrify_k(
    const int* __restrict__ bcnt, int* __restrict__ bbuf,
    int* __restrict__ rp, int* __restrict__ deg, int n, int nb)
{
    __shared__ int ent[CAP_], srt[CAP_];
    __shared__ int cnt[128], cur[128], sc[128];
    const int b = blockIdx.x, tid = threadIdx.x;
    const int blocal = b % nb, lt = b / nb;
    int c = min(bcnt[b], CAP_);
    int* seg = bbuf + (size_t)b * CAP_;

    for (int i = tid; i < c; i += 256) ent[i] = seg[i];
    if (tid < 128) cnt[tid] = 0;
    __syncthreads();
    for (int i = tid; i < c; i += 256)
        atomicAdd(&cnt[(ent[i] >> 17) & WMSK_], 1);
    __syncthreads();
    if (tid < 128) sc[tid] = cnt[tid];
    __syncthreads();
    for (int off = 1; off < 128; off <<= 1) {
        int v = (tid >= off && tid < 128) ? sc[tid - off] : 0;
        __syncthreads();
        if (tid < 128) sc[tid] += v;
        __syncthreads();
    }
    int node0 = blocal << WSH_;
    if (tid < 128) {
        int excl = sc[tid] - cnt[tid];
        cur[tid] = excl;
        if (node0 + tid < n) {
            rp[(size_t)lt * n + node0 + tid]  = b * CAP_ + excl;
            deg[(size_t)lt * n + node0 + tid] = cnt[tid];
        }
    }
    __syncthreads();
    for (int i = tid; i < c; i += 256) {
        int v = ent[i];
        int p = atomicAdd(&cur[(v >> 17) & WMSK_], 1);
        srt[p] = v & 0x1FFFF;
    }
    __syncthreads();
    for (int i = tid; i < c; i += 256) seg[i] = srt[i];
}

// ===========================================================================
// gnode6_k: FUSED conv1 = {fp32 gather of x (self folded) + 2-layer MLP +
// BN stats}. 576 threads = 96 nodes x 6 lanes. Gather phase barrier-free
// (register accum); ONE staging barrier per phase (3 total per block).
// No agg round-trip (elementwise dependency: block gathers and MLPs the
// same 96 nodes).
// ===========================================================================
__global__ __launch_bounds__(576) void gnode6_k(
    const float* __restrict__ xbase, size_t xstride,
    const int* __restrict__ rp, const int* __restrict__ deg,
    const int* __restrict__ csr,
    const float* __restrict__ wAb, const float* __restrict__ bAb,
    const float* __restrict__ wBb, const float* __restrict__ bBb,
    int t0,
    unsigned short* __restrict__ zho, size_t zstride,
    float* __restrict__ bstats, int rstride, int n)
{
    __shared__ float hin[96][7];
    __shared__ float st[96][37];
    __shared__ float ot[96][37];

    const int tid = threadIdx.x;
    const int slot = blockIdx.y;
    const int t = t0 + slot;
    const float* wa = wAb + (size_t)t * DIM_ * IN_;
    const float* ba = bAb + (size_t)t * DIM_;
    const float* wb = wBb + (size_t)t * DIM_ * DIM_;
    const float* bb = bBb + (size_t)t * DIM_;
    const float* xs = xbase + (size_t)slot * xstride;

    const int grp = tid / IN_, l = tid - grp * IN_;
    int g = blockIdx.x * 96 + grp;
    bool act = g < n;

    // phase 1: gather (register accumulation, no barriers)
    float a0 = 0.f, a1 = 0.f;
    if (act) {
        size_t off = (size_t)slot * n + g;
        int lo = rp[off], hi = lo + deg[off];
        a0 = xs[(size_t)g * IN_ + l];
        for (int e = lo; e + 1 < hi; e += 2) {
            a0 += xs[(size_t)csr[e] * IN_ + l];
            a1 += xs[(size_t)csr[e + 1] * IN_ + l];
        }
        if ((hi - lo) & 1) a0 += xs[(size_t)csr[hi - 1] * IN_ + l];
    }
    hin[grp][l] = a0 + a1;
    __syncthreads();

    // phase 2: layer A (6 threads/node, 6 outputs each)
    float y[IN_];
    #pragma unroll
    for (int q = 0; q < IN_; ++q) {
        int j = IN_ * l + q;
        float acc = ba[j];
        #pragma unroll
        for (int k = 0; k < IN_; ++k) acc = fmaf(wa[j * IN_ + k], hin[grp][k], acc);
        y[q] = fmaxf(acc, 0.f);
    }
    #pragma unroll
    for (int q = 0; q < IN_; ++q) st[grp][IN_ * l + q] = y[q];
    __syncthreads();

    // phase 3: layer B
    float out[IN_];
    #pragma unroll
    for (int q = 0; q < IN_; ++q) {
        int j = IN_ * l + q;
        float acc = bb[j];
        #pragma unroll
        for (int k = 0; k < DIM_; ++k) acc = fmaf(wb[j * DIM_ + k], st[grp][k], acc);
        out[q] = act ? fmaxf(acc, 0.f) : 0.f;
    }
    #pragma unroll
    for (int q = 0; q < IN_; ++q) ot[grp][IN_ * l + q] = out[q];
    if (act) {
        unsigned* zr = reinterpret_cast<unsigned*>(
                zho + (size_t)slot * zstride + (size_t)g * DIM_ + IN_ * l);
        zr[0] = packbf(out[0], out[1]);
        zr[1] = packbf(out[2], out[3]);
        zr[2] = packbf(out[4], out[5]);
    }
    __syncthreads();

    // phase 4: BN stats (72 threads: f = tid%36, kind = tid/36)
    if (tid < 2 * DIM_) {
        int f = tid % DIM_, kind = tid / DIM_;
        float s = 0.f;
        for (int nd = 0; nd < 96; ++nd) {
            float v = ot[nd][f];
            s += kind ? v * v : v;
        }
        bstats[((size_t)slot * rstride + blockIdx.x) * (2 * DIM_) + tid] = s;
    }
}

// ===========================================================================
// gnode36_k: FUSED convs 2,3 = {bf16 uint2 gather (self folded) + BN affine
// + 2-layer MLP + BN stats}. 576 threads = 64 nodes x 9 lanes (4 feats/lane).
// Phase 1 barrier-free (R10's proven gather36h shape); 3 barriers total
// (vs R9's 24 -> that fusion throttled the gather issue rate).
// ===========================================================================
__global__ __launch_bounds__(576) void gnode36_k(
    const unsigned short* __restrict__ zh, size_t zhstride,
    const int* __restrict__ rp, const int* __restrict__ deg,
    const int* __restrict__ csr,
    const float* __restrict__ coef,
    const float* __restrict__ wAb, const float* __restrict__ bAb,
    const float* __restrict__ wBb, const float* __restrict__ bBb,
    int t0,
    unsigned short* __restrict__ zho,
    float* __restrict__ bstats, int rstride, int n)
{
    __shared__ float hin[64][37];
    __shared__ float st[64][37];

    const int tid = threadIdx.x;
    const int slot = blockIdx.y;
    const int t = t0 + slot;
    const float* wa = wAb + (size_t)t * DIM_ * DIM_;
    const float* ba = bAb + (size_t)t * DIM_;
    const float* wb = wBb + (size_t)t * DIM_ * DIM_;
    const float* bb = bBb + (size_t)t * DIM_;
    const unsigned short* zhs = zh + (size_t)slot * zhstride;

    const int grp = tid / 9, l = tid - grp * 9;    // node-in-block, feat quad
    int g = blockIdx.x * 64 + grp;
    bool act = g < n;

    // phase 1: gather 4 features/lane via uint2, register accumulation
    float a0 = 0.f, a1 = 0.f, a2 = 0.f, a3 = 0.f;
    float b0 = 0.f, b1 = 0.f, b2 = 0.f, b3 = 0.f;
    float ds = 0.f;
    if (act) {
        size_t off = (size_t)slot * n + g;
        int lo = rp[off], d = deg[off];
        int hi = lo + d;
        ds = 1.f + (float)d;
        uint2 v = *reinterpret_cast<const uint2*>(zhs + (size_t)g * DIM_ + 4 * l);
        a0 = bf2f((unsigned short)(v.x & 0xffff));
        a1 = bf2f((unsigned short)(v.x >> 16));
        a2 = bf2f((unsigned short)(v.y & 0xffff));
        a3 = bf2f((unsigned short)(v.y >> 16));
        int e = lo;
        for (; e + 1 < hi; e += 2) {
            int s0 = csr[e], s1 = csr[e + 1];
            uint2 u0 = *reinterpret_cast<const uint2*>(zhs + (size_t)s0 * DIM_ + 4 * l);
            uint2 u1 = *reinterpret_cast<const uint2*>(zhs + (size_t)s1 * DIM_ + 4 * l);
            a0 += bf2f((unsigned short)(u0.x & 0xffff));
            a1 += bf2f((unsigned short)(u0.x >> 16));
            a2 += bf2f((unsigned short)(u0.y & 0xffff));
            a3 += bf2f((unsigned short)(u0.y >> 16));
            b0 += bf2f((unsigned short)(u1.x & 0xffff));
            b1 += bf2f((unsigned short)(u1.x >> 16));
            b2 += bf2f((unsigned short)(u1.y & 0xffff));
            b3 += bf2f((unsigned short)(u1.y >> 16));
        }
        if (e < hi) {
            uint2 u0 = *reinterpret_cast<const uint2*>(zhs + (size_t)csr[e] * DIM_ + 4 * l);
            a0 += bf2f((unsigned short)(u0.x & 0xffff));
            a1 += bf2f((unsigned short)(u0.x >> 16));
            a2 += bf2f((unsigned short)(u0.y & 0xffff));
            a3 += bf2f((unsigned short)(u0.y >> 16));
        }
    }
    // BN-of-prev affine applied at staging (coef per-lane from L1)
    {
        const float4 ca  = *reinterpret_cast<const float4*>(coef + (size_t)slot * 2 * DIM_ + 4 * l);
        const float4 cb2 = *reinterpret_cast<const float4*>(coef + (size_t)slot * 2 * DIM_ + DIM_ + 4 * l);
        hin[grp][4*l+0] = ca.x * (a0 + b0) + ds * cb2.x;
        hin[grp][4*l+1] = ca.y * (a1 + b1) + ds * cb2.y;
        hin[grp][4*l+2] = ca.z * (a2 + b2) + ds * cb2.z;
        hin[grp][4*l+3] = ca.w * (a3 + b3) + ds * cb2.w;
    }
    __syncthreads();

    // phase 2: layer A (9 threads/node, 4 output rows each)
    {
        float4 b4 = *reinterpret_cast<const float4*>(ba + 4 * l);
        float acc0 = b4.x, acc1 = b4.y, acc2 = b4.z, acc3 = b4.w;
        #pragma unroll
        for (int k = 0; k < DIM_; ++k) {
            float hv = hin[grp][k];
            acc0 = fmaf(wa[(4*l+0) * DIM_ + k], hv, acc0);
            acc1 = fmaf(wa[(4*l+1) * DIM_ + k], hv, acc1);
            acc2 = fmaf(wa[(4*l+2) * DIM_ + k], hv, acc2);
            acc3 = fmaf(wa[(4*l+3) * DIM_ + k], hv, acc3);
        }
        st[grp][4*l+0] = fmaxf(acc0, 0.f);
        st[grp][4*l+1] = fmaxf(acc1, 0.f);
        st[grp][4*l+2] = fmaxf(acc2, 0.f);
        st[grp][4*l+3] = fmaxf(acc3, 0.f);
    }
    __syncthreads();

    // phase 3: layer B -> out; z write; stage out into hin (free after ph2)
    {
        float4 b4 = *reinterpret_cast<const float4*>(bb + 4 * l);
        float acc0 = b4.x, acc1 = b4.y, acc2 = b4.z, acc3 = b4.w;
        #pragma unroll
        for (int k = 0; k < DIM_; ++k) {
            float yv = st[grp][k];
            acc0 = fmaf(wb[(4*l+0) * DIM_ + k], yv, acc0);
            acc1 = fmaf(wb[(4*l+1) * DIM_ + k], yv, acc1);
            acc2 = fmaf(wb[(4*l+2) * DIM_ + k], yv, acc2);
            acc3 = fmaf(wb[(4*l+3) * DIM_ + k], yv, acc3);
        }
        float o0 = act ? fmaxf(acc0, 0.f) : 0.f;
        float o1 = act ? fmaxf(acc1, 0.f) : 0.f;
        float o2 = act ? fmaxf(acc2, 0.f) : 0.f;
        float o3 = act ? fmaxf(acc3, 0.f) : 0.f;
        hin[grp][4*l+0] = o0; hin[grp][4*l+1] = o1;
        hin[grp][4*l+2] = o2; hin[grp][4*l+3] = o3;
        if (act) {
            unsigned* zr = reinterpret_cast<unsigned*>(
                    zho + (size_t)slot * zhstride + (size_t)g * DIM_ + 4 * l);
            zr[0] = packbf(o0, o1);
            zr[1] = packbf(o2, o3);
        }
    }
    __syncthreads();

    // phase 4: BN stats (72 threads: f = tid%36, kind = tid/36)
    if (tid < 2 * DIM_) {
        int f = tid % DIM_, kind = tid / DIM_;
        float s = 0.f;
        for (int nd = 0; nd < 64; ++nd) {
            float v = hin[nd][f];
            s += kind ? v * v : v;
        }
        bstats[((size_t)slot * rstride + blockIdx.x) * (2 * DIM_) + tid] = s;
    }
}

// ===========================================================================
// bnfin_k: reduce nrows stat rows -> fused affine coef {a, b2}. Grid (tc).
// ===========================================================================
__global__ __launch_bounds__(288) void bnfin_k(
    const float* __restrict__ bstats, int nrows, int rstride,
    const float* __restrict__ bng, const float* __restrict__ bnb,
    int t0, int c, float* __restrict__ coef, float inv_n)
{
    __shared__ float part[4][2 * DIM_];
    const int slot = blockIdx.x;
    const int t = t0 + slot;
    int tid = threadIdx.x;
    int col = tid % (2 * DIM_), quarter = tid / (2 * DIM_);
    const float* bs = bstats + (size_t)slot * rstride * (2 * DIM_);
    float s = 0.f;
    for (int i = quarter; i < nrows; i += 4) s += bs[(size_t)i * (2 * DIM_) + col];
    part[quarter][col] = s;
    __syncthreads();
    if (tid < 2 * DIM_)
        part[0][tid] = part[0][tid] + part[1][tid] + part[2][tid] + part[3][tid];
    __syncthreads();
    if (tid < DIM_) {
        float mean = part[0][tid] * inv_n;
        float var  = part[0][DIM_ + tid] * inv_n - mean * mean;
        float aa   = bng[((size_t)t * 3 + c) * DIM_ + tid] / sqrtf(var + BN_EPS);
        coef[(size_t)slot * 2 * DIM_ + tid]        = aa;
        coef[(size_t)slot * 2 * DIM_ + DIM_ + tid] = bnb[((size_t)t * 3 + c) * DIM_ + tid] - aa * mean;
    }
}

// ===========================================================================
// pool_k: per-graph mean pool over bf16 z (batch sorted), conv-3 coef.
// ===========================================================================
__global__ __launch_bounds__(288) void pool_k(
    const unsigned short* __restrict__ zh, size_t zstride,
    const float* __restrict__ coef,
    const int* __restrict__ batch, int t0,
    float* __restrict__ emb, int n)
{
    __shared__ int slo, shi;
    __shared__ float sp0[16][19], sp1[16][19];
    const int slot = blockIdx.y;
    const int t = t0 + slot;
    const int* bt = batch + (size_t)t * n;
    const unsigned short* zt = zh + (size_t)slot * zstride;
    const float* ca  = coef + (size_t)slot * 2 * DIM_;
    const float* cb2 = ca + DIM_;

    int g = blockIdx.x;
    int tid = threadIdx.x;
    if (tid == 0) {
        int lo = 0, hi = n;
        while (lo < hi) { int m = (lo + hi) >> 1; if (bt[m] < g) lo = m + 1; else hi = m; }
        slo = lo;
        int lo2 = lo, hi2 = n;
        while (lo2 < hi2) { int m = (lo2 + hi2) >> 1; if (bt[m] < g + 1) lo2 = m + 1; else hi2 = m; }
        shi = lo2;
    }
    __syncthreads();
    int lo = slo, hi = shi;
    int fp = tid % 18, j = tid / 18;    // feature pair, row group
    float acc0 = 0.f, acc1 = 0.f;
    for (int i = lo + j; i < hi; i += 16) {
        unsigned v = *reinterpret_cast<const unsigned*>(zt + (size_t)i * DIM_ + 2 * fp);
        acc0 += bf2f((unsigned short)(v & 0xffff));
        acc1 += bf2f((unsigned short)(v >> 16));
    }
    sp0[j][fp] = acc0;
    sp1[j][fp] = acc1;
    __syncthreads();
    if (tid < DIM_) {
        int f = tid, fpair = f >> 1, hi_ = f & 1;
        float s = 0.f;
        #pragma unroll
        for (int jj = 0; jj < 16; ++jj)
            s += hi_ ? sp1[jj][fpair] : sp0[jj][fpair];
        int cnt = hi - lo;
        float val = 0.f;
        if (cnt > 0) val = ca[f] * (s / (float)cnt) + cb2[f];
        emb[(size_t)g * (T_ * DIM_) + t * DIM_ + f] = val;
    }
}

// ===========================================================================
// head_k: one 64-thread block per graph, layers staged through LDS.
// ===========================================================================
__global__ __launch_bounds__(64) void head_k(
    const float* __restrict__ emb,
    const float* __restrict__ hw1, const float* __restrict__ hb1,
    const float* __restrict__ hw2, const float* __restrict__ hb2,
    const float* __restrict__ hw3, const float* __restrict__ hb3,
    float* __restrict__ out, int ng)
{
    const int EMB = T_ * DIM_;
    int g = blockIdx.x;
    if (g >= ng) return;
    __shared__ float se[EMB], st1[LIN_], st2[OUT_];
    int tid = threadIdx.x;
    for (int i = tid; i < EMB; i += 64) se[i] = emb[(size_t)g * EMB + i];
    __syncthreads();
    if (tid < LIN_) {
        float acc = hb1[tid];
        #pragma unroll
        for (int k = 0; k < EMB; ++k) acc = fmaf(hw1[tid * EMB + k], se[k], acc);
        st1[tid] = fmaxf(acc, 0.f);
    }
    __syncthreads();
    if (tid < OUT_) {
        float acc = hb2[tid];
        #pragma unroll
        for (int k = 0; k < LIN_; ++k) acc = fmaf(hw2[tid * LIN_ + k], st1[k], acc);
        st2[tid] = fmaxf(acc, 0.f);
    }
    __syncthreads();
    if (tid == 0) {
        float acc = hb3[0];
        #pragma unroll
        for (int k = 0; k < OUT_; ++k) acc = fmaf(hw3[k], st2[k], acc);
        out[g] = 1.f / (1.f + expf(-acc));
    }
}

// ===========================================================================
extern "C" void kernel_launch(void* const* d_in, const int* in_sizes, int n_in,
                              void* d_out, int out_size, void* d_ws, size_t ws_size,
                              hipStream_t stream)
{
    const float* x     = (const float*)d_in[0];
    const int*   ei    = (const int*)d_in[1];
    const int*   batch = (const int*)d_in[2];
    const float* wA[3] = {(const float*)d_in[3], (const float*)d_in[7], (const float*)d_in[11]};
    const float* bA[3] = {(const float*)d_in[4], (const float*)d_in[8], (const float*)d_in[12]};
    const float* wB[3] = {(const float*)d_in[5], (const float*)d_in[9], (const float*)d_in[13]};
    const float* bB[3] = {(const float*)d_in[6], (const float*)d_in[10], (const float*)d_in[14]};
    const float* bng = (const float*)d_in[15];
    const float* bnb = (const float*)d_in[16];
    const float* hw1 = (const float*)d_in[17];
    const float* hb1 = (const float*)d_in[18];
    const float* hw2 = (const float*)d_in[19];
    const float* hb2 = (const float*)d_in[20];
    const float* hw3 = (const float*)d_in[21];
    const float* hb3 = (const float*)d_in[22];

    const int N = in_sizes[2] / T_;
    const int E = in_sizes[1] / (2 * T_);
    const int G = out_size;
    const int NB = (N + WMSK_) / 128;
    const int gn6  = (N + 95) / 96;           // gnode6 blocks / stat rows
    const int gn36 = (N + 63) / 64;           // gnode36 blocks / stat rows
    const float inv_n = 1.0f / (float)N;
    const int gbin = (E + TILE_ - 1) / TILE_;

    const size_t bufN = (size_t)N * DIM_;
    auto need = [&](int tc) -> size_t {
        size_t f = (size_t)tc * gn36 * 2 * DIM_                // bstats
                 + (size_t)tc * 2 * DIM_                       // coef
                 + (size_t)G * T_ * DIM_;                      // emb
        size_t hs = 2 * (size_t)tc * bufN;                     // zhA + zhB
        size_t ii = (size_t)tc * NB + 2 * (size_t)tc * N + (size_t)tc * NB * CAP_;
        return f * sizeof(float) + hs * sizeof(unsigned short) + ii * sizeof(int);
    };
    const int tcnt = (need(2) <= ws_size) ? 2 : 1;

    char* ws = (char*)d_ws;
    float* bstats = (float*)ws;                               // tc*gn36*72
    float* coef   = bstats + (size_t)tcnt * gn36 * 2 * DIM_;  // tc*72
    float* emb    = coef + (size_t)tcnt * 2 * DIM_;           // G*72
    unsigned short* zhA = (unsigned short*)(emb + (size_t)G * T_ * DIM_);
    unsigned short* zhB = zhA + (size_t)tcnt * bufN;
    int*   bcnt   = (int*)(zhB + (size_t)tcnt * bufN);        // tc*NB
    int*   rp     = bcnt + (size_t)tcnt * NB;                 // tc*N
    int*   deg    = rp + (size_t)tcnt * N;                    // tc*N
    int*   bbuf   = deg + (size_t)tcnt * N;                   // tc*NB*CAP_

    float* outp = (float*)d_out;

    for (int t0 = 0; t0 < T_; t0 += tcnt) {
        const int tc = tcnt;

        hipMemsetAsync(bcnt, 0, (size_t)tc * NB * sizeof(int), stream);
        binsort_k<<<tc * gbin, 256, 0, stream>>>(ei, t0, gbin, bcnt, bbuf, E, NB);
        csrify_k<<<tc * NB, 256, 0, stream>>>(bcnt, bbuf, rp, deg, N, NB);

        // conv1 fused: x -> zhA
        gnode6_k<<<dim3(gn6, tc), 576, 0, stream>>>(
                x + (size_t)t0 * N * IN_, (size_t)N * IN_,
                rp, deg, bbuf, wA[0], bA[0], wB[0], bB[0], t0,
                zhA, bufN, bstats, gn36, N);
        bnfin_k<<<tc, 288, 0, stream>>>(bstats, gn6, gn36, bng, bnb, t0, 0, coef, inv_n);

        // conv2 fused: zhA -> zhB
        gnode36_k<<<dim3(gn36, tc), 576, 0, stream>>>(
                zhA, bufN, rp, deg, bbuf, coef,
                wA[1], bA[1], wB[1], bB[1], t0, zhB, bstats, gn36, N);
        bnfin_k<<<tc, 288, 0, stream>>>(bstats, gn36, gn36, bng, bnb, t0, 1, coef, inv_n);

        // conv3 fused: zhB -> zhA
        gnode36_k<<<dim3(gn36, tc), 576, 0, stream>>>(
                zhB, bufN, rp, deg, bbuf, coef,
                wA[2], bA[2], wB[2], bB[2], t0, zhA, bstats, gn36, N);
        bnfin_k<<<tc, 288, 0, stream>>>(bstats, gn36, gn36, bng, bnb, t0, 2, coef, inv_n);

        pool_k<<<dim3(G, tc), 288, 0, stream>>>(zhA, bufN, coef, batch, t0, emb, N);
    }
    head_k<<<G, 64, 0, stream>>>(emb, hw1, hb1, hw2, hb2, hw3, hb3, outp, G);
}

// Round 12
// 483.073 us; speedup vs baseline: 1.8922x; 1.8922x over previous
//
#include <hip/hip_runtime.h>

#define T_   2
#define IN_  6
#define DIM_ 36
#define LIN_ 54
#define OUT_ 18
#define BN_EPS 1e-5f

#define WSH_   7        // bucket width = 128 dst nodes
#define WMSK_  127
#define CAP_   2560     // per-bucket capacity (mean 2046, 11 sigma headroom)
#define TILE_  12288    // edges per binsort block (48KB tile; 16 entries/bucket)
#define NBMAX_ 1024     // max buckets supported by in-LDS scan

__device__ __forceinline__ unsigned short f2bf(float f) {
    unsigned u = __float_as_uint(f);
    unsigned r = (u + 0x7FFFu + ((u >> 16) & 1u)) >> 16;    // RNE
    return (unsigned short)r;
}
__device__ __forceinline__ float bf2f(unsigned short h) {
    return __uint_as_float(((unsigned)h) << 16);
}
__device__ __forceinline__ unsigned packbf(float a, float b) {
    return (unsigned)f2bf(a) | ((unsigned)f2bf(b) << 16);
}

// ===========================================================================
// binsort_k: bin edges by dst bucket with LDS staging; coalesced packed
// writes (src 17b | dstoff 7b). Copy-out uses 16-LANE SUB-GROUPS per bucket
// (R10's wave-per-bucket left ~56/64 lanes idle at ~8 entries/bucket/tile).
// ===========================================================================
__global__ __launch_bounds__(256) void binsort_k(
    const int* __restrict__ ei, int t0, int gbin,
    int* __restrict__ bcnt, int* __restrict__ bbuf, int ne, int nb)
{
    __shared__ int cntl[NBMAX_], cursl[NBMAX_], gbasel[NBMAX_];
    __shared__ int aux[256];
    __shared__ int sortedl[TILE_];

    const int tid  = threadIdx.x;
    const int lt   = blockIdx.x / gbin;
    const int tile = blockIdx.x % gbin;
    const int base = tile * TILE_;
    const int cnt_e = min(TILE_, ne - base);
    const int* srcp = ei + (size_t)(t0 + lt) * 2 * ne;
    const int* dstp = srcp + ne;
    int* bcnt_t = bcnt + (size_t)lt * nb;

    for (int i = tid; i < NBMAX_; i += 256) cntl[i] = 0;
    __syncthreads();

    for (int i = tid; i < cnt_e; i += 256)
        atomicAdd(&cntl[dstp[base + i] >> WSH_], 1);
    __syncthreads();

    int t4 = tid * 4;
    int c0 = cntl[t4+0], c1 = cntl[t4+1], c2 = cntl[t4+2], c3 = cntl[t4+3];
    int lsum = c0 + c1 + c2 + c3;
    aux[tid] = lsum;
    __syncthreads();
    for (int off = 1; off < 256; off <<= 1) {
        int v = (tid >= off) ? aux[tid - off] : 0;
        __syncthreads();
        aux[tid] += v;
        __syncthreads();
    }
    int eb = aux[tid] - lsum;
    cursl[t4+0] = eb;
    cursl[t4+1] = eb + c0;
    cursl[t4+2] = eb + c0 + c1;
    cursl[t4+3] = eb + c0 + c1 + c2;
    __syncthreads();

    for (int b = tid; b < nb; b += 256) {
        int c = cntl[b];
        gbasel[b] = c ? atomicAdd(&bcnt_t[b], c) : 0;
    }
    __syncthreads();

    for (int i = tid; i < cnt_e; i += 256) {
        int s = srcp[base + i], d = dstp[base + i];
        int p = atomicAdd(&cursl[d >> WSH_], 1);
        sortedl[p] = s | ((d & WMSK_) << 17);
    }
    __syncthreads();

    // copy out: 16 lanes per bucket, 16 buckets concurrently per block
    int grp16 = tid >> 4, ln16 = tid & 15;
    for (int b = grp16; b < nb; b += 16) {
        int c = cntl[b];
        if (!c) continue;
        int lb = cursl[b] - c;
        int gb = gbasel[b];
        size_t ga = ((size_t)lt * nb + b) * CAP_ + gb;
        for (int i = ln16; i < c; i += 16)
            if (gb + i < CAP_) bbuf[ga + i] = sortedl[lb + i];
    }
}

// ===========================================================================
// csrify_k: one block per (t,bucket): sort bucket by dst node in LDS, write
// back coalesced (unpacked src), emit rp (global into bbuf) and deg.
// ===========================================================================
__global__ __launch_bounds__(256) void csrify_k(
    const int* __restrict__ bcnt, int* __restrict__ bbuf,
    int* __restrict__ rp, int* __restrict__ deg, int n, int nb)
{
    __shared__ int ent[CAP_], srt[CAP_];
    __shared__ int cnt[128], cur[128], sc[128];
    const int b = blockIdx.x, tid = threadIdx.x;
    const int blocal = b % nb, lt = b / nb;
    int c = min(bcnt[b], CAP_);
    int* seg = bbuf + (size_t)b * CAP_;

    for (int i = tid; i < c; i += 256) ent[i] = seg[i];
    if (tid < 128) cnt[tid] = 0;
    __syncthreads();
    for (int i = tid; i < c; i += 256)
        atomicAdd(&cnt[(ent[i] >> 17) & WMSK_], 1);
    __syncthreads();
    if (tid < 128) sc[tid] = cnt[tid];
    __syncthreads();
    for (int off = 1; off < 128; off <<= 1) {
        int v = (tid >= off && tid < 128) ? sc[tid - off] : 0;
        __syncthreads();
        if (tid < 128) sc[tid] += v;
        __syncthreads();
    }
    int node0 = blocal << WSH_;
    if (tid < 128) {
        int excl = sc[tid] - cnt[tid];
        cur[tid] = excl;
        if (node0 + tid < n) {
            rp[(size_t)lt * n + node0 + tid]  = b * CAP_ + excl;
            deg[(size_t)lt * n + node0 + tid] = cnt[tid];
        }
    }
    __syncthreads();
    for (int i = tid; i < c; i += 256) {
        int v = ent[i];
        int p = atomicAdd(&cur[(v >> 17) & WMSK_], 1);
        srt[p] = v & 0x1FFFF;
    }
    __syncthreads();
    for (int i = tid; i < c; i += 256) seg[i] = srt[i];
}

// ===========================================================================
// gather_k (conv1, D=6, fp32): agg[i] = x[i] + sum_{nbr} x[nbr].
// ===========================================================================
template<int D>
__global__ __launch_bounds__(576) void gather_k(
        const float* __restrict__ hbase, size_t hstride,
        const int* __restrict__ rp, const int* __restrict__ deg,
        const int* __restrict__ csr, float* __restrict__ agg,
        size_t astride, int n)
{
    const int NPB = 576 / D;
    const int slot = blockIdx.y;
    const float* h = hbase + (size_t)slot * hstride;
    int g = blockIdx.x * NPB + threadIdx.x / D;
    int lane = threadIdx.x % D;
    if (g >= n) return;
    int lo = rp[(size_t)slot * n + g], hi = lo + deg[(size_t)slot * n + g];
    float a0 = h[(size_t)g * D + lane], a1 = 0.f, a2 = 0.f, a3 = 0.f;
    int e = lo;
    for (; e + 3 < hi; e += 4) {
        int s0 = csr[e], s1 = csr[e + 1], s2 = csr[e + 2], s3 = csr[e + 3];
        a0 += h[(size_t)s0 * D + lane];
        a1 += h[(size_t)s1 * D + lane];
        a2 += h[(size_t)s2 * D + lane];
        a3 += h[(size_t)s3 * D + lane];
    }
    for (; e < hi; ++e) a0 += h[(size_t)csr[e] * D + lane];
    agg[(size_t)slot * astride + (size_t)g * D + lane] = (a0 + a1) + (a2 + a3);
}

// ===========================================================================
// gather36h_k: bf16 rows, 9 lanes/node (4 features/lane via uint2 = 8B/lane).
// agg[i] = self + sum_nbr, fp32 out. Barrier-free, register accumulation.
// (Triple-confirmed R5/R9/R11: this must NOT be fused with the MLP.)
// ===========================================================================
__global__ __launch_bounds__(576) void gather36h_k(
        const unsigned short* __restrict__ zh, size_t zhstride,
        const int* __restrict__ rp, const int* __restrict__ deg,
        const int* __restrict__ csr, float* __restrict__ agg,
        size_t astride, int n)
{
    const int slot = blockIdx.y;
    const unsigned short* zhs = zh + (size_t)slot * zhstride;
    int g = blockIdx.x * 64 + threadIdx.x / 9;
    int lane = threadIdx.x % 9;                  // features 4*lane .. 4*lane+3
    if (g >= n) return;
    size_t off = (size_t)slot * n + g;
    int lo = rp[off], hi = lo + deg[off];

    uint2 v = *reinterpret_cast<const uint2*>(zhs + (size_t)g * DIM_ + 4 * lane);
    float a0 = bf2f((unsigned short)(v.x & 0xffff));
    float a1 = bf2f((unsigned short)(v.x >> 16));
    float a2 = bf2f((unsigned short)(v.y & 0xffff));
    float a3 = bf2f((unsigned short)(v.y >> 16));
    float b0 = 0.f, b1 = 0.f, b2 = 0.f, b3 = 0.f;

    int e = lo;
    for (; e + 1 < hi; e += 2) {
        int s0 = csr[e], s1 = csr[e + 1];
        uint2 u0 = *reinterpret_cast<const uint2*>(zhs + (size_t)s0 * DIM_ + 4 * lane);
        uint2 u1 = *reinterpret_cast<const uint2*>(zhs + (size_t)s1 * DIM_ + 4 * lane);
        a0 += bf2f((unsigned short)(u0.x & 0xffff));
        a1 += bf2f((unsigned short)(u0.x >> 16));
        a2 += bf2f((unsigned short)(u0.y & 0xffff));
        a3 += bf2f((unsigned short)(u0.y >> 16));
        b0 += bf2f((unsigned short)(u1.x & 0xffff));
        b1 += bf2f((unsigned short)(u1.x >> 16));
        b2 += bf2f((unsigned short)(u1.y & 0xffff));
        b3 += bf2f((unsigned short)(u1.y >> 16));
    }
    if (e < hi) {
        uint2 u0 = *reinterpret_cast<const uint2*>(zhs + (size_t)csr[e] * DIM_ + 4 * lane);
        a0 += bf2f((unsigned short)(u0.x & 0xffff));
        a1 += bf2f((unsigned short)(u0.x >> 16));
        a2 += bf2f((unsigned short)(u0.y & 0xffff));
        a3 += bf2f((unsigned short)(u0.y >> 16));
    }
    float4 r; r.x = a0 + b0; r.y = a1 + b1; r.z = a2 + b2; r.w = a3 + b3;
    *reinterpret_cast<float4*>(agg + (size_t)slot * astride + (size_t)g * DIM_ + 4 * lane) = r;
}

// ===========================================================================
// node6_k (conv1 MLP): hin = agg; y = relu(Wa hin+ba); out = relu(Wb y+bb);
// bf16 z out; per-block BN stat row. Weights via wave-uniform s_load.
// ===========================================================================
__global__ __launch_bounds__(256) void node6_k(
    const float* __restrict__ agg, size_t astride,
    const float* __restrict__ wAb, const float* __restrict__ bAb,
    const float* __restrict__ wBb, const float* __restrict__ bBb,
    int t0,
    unsigned short* __restrict__ zho, size_t zstride,
    float* __restrict__ bstats, int gn, int n)
{
    __shared__ float sstat[4][2 * DIM_];
    const int slot = blockIdx.y;
    const int t = t0 + slot;
    const float* wa = wAb + (size_t)t * DIM_ * IN_;
    const float* ba = bAb + (size_t)t * DIM_;
    const float* wb = wBb + (size_t)t * DIM_ * DIM_;
    const float* bb = bBb + (size_t)t * DIM_;

    int node = blockIdx.x * 256 + threadIdx.x;
    bool active = node < n;

    float hin[IN_];
    if (active) {
        const float2* ar2 = reinterpret_cast<const float2*>(
                agg + (size_t)slot * astride + (size_t)node * IN_);
        float2 v0 = ar2[0], v1 = ar2[1], v2 = ar2[2];
        hin[0] = v0.x; hin[1] = v0.y; hin[2] = v1.x;
        hin[3] = v1.y; hin[4] = v2.x; hin[5] = v2.y;
    } else {
        #pragma unroll
        for (int k = 0; k < IN_; ++k) hin[k] = 0.f;
    }

    float y[DIM_];
    #pragma unroll
    for (int j = 0; j < DIM_; ++j) {
        float acc = ba[j];
        #pragma unroll
        for (int k = 0; k < IN_; ++k) acc = fmaf(wa[j * IN_ + k], hin[k], acc);
        y[j] = fmaxf(acc, 0.f);
    }
    float out[DIM_];
    #pragma unroll
    for (int j = 0; j < DIM_; ++j) {
        float acc = bb[j];
        #pragma unroll
        for (int k = 0; k < DIM_; ++k) acc = fmaf(wb[j * DIM_ + k], y[k], acc);
        out[j] = active ? fmaxf(acc, 0.f) : 0.f;
    }

    if (active) {
        unsigned* zr = reinterpret_cast<unsigned*>(
                zho + (size_t)slot * zstride + (size_t)node * DIM_);
        #pragma unroll
        for (int j = 0; j < DIM_ / 2; ++j) zr[j] = packbf(out[2*j], out[2*j+1]);
    }

    int wid = threadIdx.x >> 6, lane = threadIdx.x & 63;
    #pragma unroll
    for (int j = 0; j < DIM_; ++j) {
        float s = out[j], sq = out[j] * out[j];
        for (int off = 32; off; off >>= 1) {
            s  += __shfl_down(s,  off);
            sq += __shfl_down(sq, off);
        }
        if (lane == 0) { sstat[wid][j] = s; sstat[wid][DIM_ + j] = sq; }
    }
    __syncthreads();
    if (threadIdx.x < 2 * DIM_) {
        float s = sstat[0][threadIdx.x] + sstat[1][threadIdx.x]
                + sstat[2][threadIdx.x] + sstat[3][threadIdx.x];
        bstats[((size_t)slot * gn + blockIdx.x) * (2 * DIM_) + threadIdx.x] = s;
    }
}

// ===========================================================================
// node36_k (convs 2,3 MLP): hin = a.agg + (1+deg).b2 (agg already = h+S);
// y = relu(Wa hin+ba); out = relu(Wb y+bb); bf16 z out; stat row per block.
// ===========================================================================
__global__ __launch_bounds__(256) void node36_k(
    const float* __restrict__ agg, size_t astride,
    const int* __restrict__ deg,
    const float* __restrict__ coef,
    const float* __restrict__ wAb, const float* __restrict__ bAb,
    const float* __restrict__ wBb, const float* __restrict__ bBb,
    int t0,
    unsigned short* __restrict__ zho, size_t zstride,
    float* __restrict__ bstats, int gn, int n)
{
    __shared__ float sstat[4][2 * DIM_];
    const int slot = blockIdx.y;
    const int t = t0 + slot;
    const float* wa = wAb + (size_t)t * DIM_ * DIM_;
    const float* ba = bAb + (size_t)t * DIM_;
    const float* wb = wBb + (size_t)t * DIM_ * DIM_;
    const float* bb = bBb + (size_t)t * DIM_;
    const float* ca  = coef + (size_t)slot * 2 * DIM_;
    const float* cb2 = ca + DIM_;

    int node = blockIdx.x * 256 + threadIdx.x;
    bool active = node < n;

    float hin[DIM_];
    if (active) {
        const float4* ar4 = reinterpret_cast<const float4*>(
                agg + (size_t)slot * astride + (size_t)node * DIM_);
        #pragma unroll
        for (int q = 0; q < 9; ++q) {
            float4 av = ar4[q];
            hin[4*q+0] = av.x; hin[4*q+1] = av.y;
            hin[4*q+2] = av.z; hin[4*q+3] = av.w;
        }
        float ds = 1.0f + (float)deg[(size_t)slot * n + node];
        #pragma unroll
        for (int k = 0; k < DIM_; ++k)
            hin[k] = ca[k] * hin[k] + ds * cb2[k];
    } else {
        #pragma unroll
        for (int k = 0; k < DIM_; ++k) hin[k] = 0.f;
    }

    float y[DIM_];
    #pragma unroll
    for (int j = 0; j < DIM_; ++j) {
        float acc = ba[j];
        #pragma unroll
        for (int k = 0; k < DIM_; ++k) acc = fmaf(wa[j * DIM_ + k], hin[k], acc);
        y[j] = fmaxf(acc, 0.f);
    }
    float out[DIM_];
    #pragma unroll
    for (int j = 0; j < DIM_; ++j) {
        float acc = bb[j];
        #pragma unroll
        for (int k = 0; k < DIM_; ++k) acc = fmaf(wb[j * DIM_ + k], y[k], acc);
        out[j] = active ? fmaxf(acc, 0.f) : 0.f;
    }

    if (active) {
        unsigned* zr = reinterpret_cast<unsigned*>(
                zho + (size_t)slot * zstride + (size_t)node * DIM_);
        #pragma unroll
        for (int j = 0; j < DIM_ / 2; ++j) zr[j] = packbf(out[2*j], out[2*j+1]);
    }

    int wid = threadIdx.x >> 6, lane = threadIdx.x & 63;
    #pragma unroll
    for (int j = 0; j < DIM_; ++j) {
        float s = out[j], sq = out[j] * out[j];
        for (int off = 32; off; off >>= 1) {
            s  += __shfl_down(s,  off);
            sq += __shfl_down(sq, off);
        }
        if (lane == 0) { sstat[wid][j] = s; sstat[wid][DIM_ + j] = sq; }
    }
    __syncthreads();
    if (threadIdx.x < 2 * DIM_) {
        float s = sstat[0][threadIdx.x] + sstat[1][threadIdx.x]
                + sstat[2][threadIdx.x] + sstat[3][threadIdx.x];
        bstats[((size_t)slot * gn + blockIdx.x) * (2 * DIM_) + threadIdx.x] = s;
    }
}

// ===========================================================================
// bnfin_k: reduce nrows stat rows -> fused affine coef {a, b2}. Grid (tc).
// ===========================================================================
__global__ __launch_bounds__(288) void bnfin_k(
    const float* __restrict__ bstats, int nrows, int rstride,
    const float* __restrict__ bng, const float* __restrict__ bnb,
    int t0, int c, float* __restrict__ coef, float inv_n)
{
    __shared__ float part[4][2 * DIM_];
    const int slot = blockIdx.x;
    const int t = t0 + slot;
    int tid = threadIdx.x;
    int col = tid % (2 * DIM_), quarter = tid / (2 * DIM_);
    const float* bs = bstats + (size_t)slot * rstride * (2 * DIM_);
    float s = 0.f;
    for (int i = quarter; i < nrows; i += 4) s += bs[(size_t)i * (2 * DIM_) + col];
    part[quarter][col] = s;
    __syncthreads();
    if (tid < 2 * DIM_)
        part[0][tid] = part[0][tid] + part[1][tid] + part[2][tid] + part[3][tid];
    __syncthreads();
    if (tid < DIM_) {
        float mean = part[0][tid] * inv_n;
        float var  = part[0][DIM_ + tid] * inv_n - mean * mean;
        float aa   = bng[((size_t)t * 3 + c) * DIM_ + tid] / sqrtf(var + BN_EPS);
        coef[(size_t)slot * 2 * DIM_ + tid]        = aa;
        coef[(size_t)slot * 2 * DIM_ + DIM_ + tid] = bnb[((size_t)t * 3 + c) * DIM_ + tid] - aa * mean;
    }
}

// ===========================================================================
// pool_k: per-graph mean pool over bf16 z (batch sorted), conv-3 coef.
// 288 threads = 16 row-groups x 18 feature-pairs (uint loads).
// ===========================================================================
__global__ __launch_bounds__(288) void pool_k(
    const unsigned short* __restrict__ zh, size_t zstride,
    const float* __restrict__ coef,
    const int* __restrict__ batch, int t0,
    float* __restrict__ emb, int n)
{
    __shared__ int slo, shi;
    __shared__ float sp0[16][19], sp1[16][19];
    const int slot = blockIdx.y;
    const int t = t0 + slot;
    const int* bt = batch + (size_t)t * n;
    const unsigned short* zt = zh + (size_t)slot * zstride;
    const float* ca  = coef + (size_t)slot * 2 * DIM_;
    const float* cb2 = ca + DIM_;

    int g = blockIdx.x;
    int tid = threadIdx.x;
    if (tid == 0) {
        int lo = 0, hi = n;
        while (lo < hi) { int m = (lo + hi) >> 1; if (bt[m] < g) lo = m + 1; else hi = m; }
        slo = lo;
        int lo2 = lo, hi2 = n;
        while (lo2 < hi2) { int m = (lo2 + hi2) >> 1; if (bt[m] < g + 1) lo2 = m + 1; else hi2 = m; }
        shi = lo2;
    }
    __syncthreads();
    int lo = slo, hi = shi;
    int fp = tid % 18, j = tid / 18;    // feature pair, row group
    float acc0 = 0.f, acc1 = 0.f;
    for (int i = lo + j; i < hi; i += 16) {
        unsigned v = *reinterpret_cast<const unsigned*>(zt + (size_t)i * DIM_ + 2 * fp);
        acc0 += bf2f((unsigned short)(v & 0xffff));
        acc1 += bf2f((unsigned short)(v >> 16));
    }
    sp0[j][fp] = acc0;
    sp1[j][fp] = acc1;
    __syncthreads();
    if (tid < DIM_) {
        int f = tid, fpair = f >> 1, hi_ = f & 1;
        float s = 0.f;
        #pragma unroll
        for (int jj = 0; jj < 16; ++jj)
            s += hi_ ? sp1[jj][fpair] : sp0[jj][fpair];
        int cnt = hi - lo;
        float val = 0.f;
        if (cnt > 0) val = ca[f] * (s / (float)cnt) + cb2[f];
        emb[(size_t)g * (T_ * DIM_) + t * DIM_ + f] = val;
    }
}

// ===========================================================================
// head_k: one 64-thread block per graph, layers staged through LDS.
// ===========================================================================
__global__ __launch_bounds__(64) void head_k(
    const float* __restrict__ emb,
    const float* __restrict__ hw1, const float* __restrict__ hb1,
    const float* __restrict__ hw2, const float* __restrict__ hb2,
    const float* __restrict__ hw3, const float* __restrict__ hb3,
    float* __restrict__ out, int ng)
{
    const int EMB = T_ * DIM_;
    int g = blockIdx.x;
    if (g >= ng) return;
    __shared__ float se[EMB], st1[LIN_], st2[OUT_];
    int tid = threadIdx.x;
    for (int i = tid; i < EMB; i += 64) se[i] = emb[(size_t)g * EMB + i];
    __syncthreads();
    if (tid < LIN_) {
        float acc = hb1[tid];
        #pragma unroll
        for (int k = 0; k < EMB; ++k) acc = fmaf(hw1[tid * EMB + k], se[k], acc);
        st1[tid] = fmaxf(acc, 0.f);
    }
    __syncthreads();
    if (tid < OUT_) {
        float acc = hb2[tid];
        #pragma unroll
        for (int k = 0; k < LIN_; ++k) acc = fmaf(hw2[tid * LIN_ + k], st1[k], acc);
        st2[tid] = fmaxf(acc, 0.f);
    }
    __syncthreads();
    if (tid == 0) {
        float acc = hb3[0];
        #pragma unroll
        for (int k = 0; k < OUT_; ++k) acc = fmaf(hw3[k], st2[k], acc);
        out[g] = 1.f / (1.f + expf(-acc));
    }
}

// ===========================================================================
extern "C" void kernel_launch(void* const* d_in, const int* in_sizes, int n_in,
                              void* d_out, int out_size, void* d_ws, size_t ws_size,
                              hipStream_t stream)
{
    const float* x     = (const float*)d_in[0];
    const int*   ei    = (const int*)d_in[1];
    const int*   batch = (const int*)d_in[2];
    const float* wA[3] = {(const float*)d_in[3], (const float*)d_in[7], (const float*)d_in[11]};
    const float* bA[3] = {(const float*)d_in[4], (const float*)d_in[8], (const float*)d_in[12]};
    const float* wB[3] = {(const float*)d_in[5], (const float*)d_in[9], (const float*)d_in[13]};
    const float* bB[3] = {(const float*)d_in[6], (const float*)d_in[10], (const float*)d_in[14]};
    const float* bng = (const float*)d_in[15];
    const float* bnb = (const float*)d_in[16];
    const float* hw1 = (const float*)d_in[17];
    const float* hb1 = (const float*)d_in[18];
    const float* hw2 = (const float*)d_in[19];
    const float* hb2 = (const float*)d_in[20];
    const float* hw3 = (const float*)d_in[21];
    const float* hb3 = (const float*)d_in[22];

    const int N = in_sizes[2] / T_;
    const int E = in_sizes[1] / (2 * T_);
    const int G = out_size;
    const int NB = (N + WMSK_) / 128;
    const int gn = (N + 255) / 256;
    const float inv_n = 1.0f / (float)N;
    const int gbin = (E + TILE_ - 1) / TILE_;

    const size_t bufN = (size_t)N * DIM_;
    auto need = [&](int tc) -> size_t {
        size_t f = (size_t)tc * bufN                           // agg fp32
                 + (size_t)tc * gn * 2 * DIM_                  // bstats
                 + (size_t)tc * 2 * DIM_                       // coef
                 + (size_t)G * T_ * DIM_;                      // emb
        size_t hs = 2 * (size_t)tc * bufN;                     // zhA + zhB
        size_t ii = (size_t)tc * NB + 2 * (size_t)tc * N + (size_t)tc * NB * CAP_;
        return f * sizeof(float) + hs * sizeof(unsigned short) + ii * sizeof(int);
    };
    const int tcnt = (need(2) <= ws_size) ? 2 : 1;

    char* ws = (char*)d_ws;
    float* agg    = (float*)ws;                               // tc*N*36 fp32
    float* bstats = agg + (size_t)tcnt * bufN;                // tc*gn*72
    float* coef   = bstats + (size_t)tcnt * gn * 2 * DIM_;    // tc*72
    float* emb    = coef + (size_t)tcnt * 2 * DIM_;           // G*72
    unsigned short* zhA = (unsigned short*)(emb + (size_t)G * T_ * DIM_);
    unsigned short* zhB = zhA + (size_t)tcnt * bufN;
    int*   bcnt   = (int*)(zhB + (size_t)tcnt * bufN);        // tc*NB
    int*   rp     = bcnt + (size_t)tcnt * NB;                 // tc*N
    int*   deg    = rp + (size_t)tcnt * N;                    // tc*N
    int*   bbuf   = deg + (size_t)tcnt * N;                   // tc*NB*CAP_

    float* outp = (float*)d_out;

    for (int t0 = 0; t0 < T_; t0 += tcnt) {
        const int tc = tcnt;

        hipMemsetAsync(bcnt, 0, (size_t)tc * NB * sizeof(int), stream);
        binsort_k<<<tc * gbin, 256, 0, stream>>>(ei, t0, gbin, bcnt, bbuf, E, NB);
        csrify_k<<<tc * NB, 256, 0, stream>>>(bcnt, bbuf, rp, deg, N, NB);

        // conv1: fp32 gather of x (self folded), MLP -> bf16 zhA
        gather_k<IN_><<<dim3((N + 95) / 96, tc), 576, 0, stream>>>(
                x + (size_t)t0 * N * IN_, (size_t)N * IN_,
                rp, deg, bbuf, agg, (size_t)N * IN_, N);
        node6_k<<<dim3(gn, tc), 256, 0, stream>>>(
                agg, (size_t)N * IN_, wA[0], bA[0], wB[0], bB[0], t0,
                zhA, bufN, bstats, gn, N);
        bnfin_k<<<tc, 288, 0, stream>>>(bstats, gn, gn, bng, bnb, t0, 0, coef, inv_n);

        // conv2: bf16 gather zhA -> fp32 agg; MLP -> bf16 zhB
        gather36h_k<<<dim3((N + 63) / 64, tc), 576, 0, stream>>>(
                zhA, bufN, rp, deg, bbuf, agg, bufN, N);
        node36_k<<<dim3(gn, tc), 256, 0, stream>>>(
                agg, bufN, deg, coef, wA[1], bA[1], wB[1], bB[1], t0,
                zhB, bufN, bstats, gn, N);
        bnfin_k<<<tc, 288, 0, stream>>>(bstats, gn, gn, bng, bnb, t0, 1, coef, inv_n);

        // conv3: bf16 gather zhB -> fp32 agg; MLP -> bf16 zhA
        gather36h_k<<<dim3((N + 63) / 64, tc), 576, 0, stream>>>(
                zhB, bufN, rp, deg, bbuf, agg, bufN, N);
        node36_k<<<dim3(gn, tc), 256, 0, stream>>>(
                agg, bufN, deg, coef, wA[2], bA[2], wB[2], bB[2], t0,
                zhA, bufN, bstats, gn, N);
        bnfin_k<<<tc, 288, 0, stream>>>(bstats, gn, gn, bng, bnb, t0, 2, coef, inv_n);

        pool_k<<<dim3(G, tc), 288, 0, stream>>>(zhA, bufN, coef, batch, t0, emb, N);
    }
    head_k<<<G, 64, 0, stream>>>(emb, hw1, hb1, hw2, hb2, hw3, hb3, outp, G);
}